// Round 1
// baseline (855.344 us; speedup 1.0000x reference)
//
#include <hip/hip_runtime.h>
#include <cstdint>
#include <cstddef>

// Shapes (fixed by the problem)
// B=8 H=16 KVH=2 D=128 S=16 T=8192 HID=2048, G=8
// d_out = [out 262144][new_k 16777216][new_v 16777216] fp32

static __device__ __forceinline__ unsigned short f2bf(float f) {
  unsigned int u = __float_as_uint(f);
  u = u + 0x7FFFu + ((u >> 16) & 1u);   // RNE
  return (unsigned short)(u >> 16);
}
static __device__ __forceinline__ float bf2f(unsigned short u) {
  return __uint_as_float(((unsigned int)u) << 16);
}
static __device__ __forceinline__ void unpack8(uint4 v, float* f) {
  f[0] = __uint_as_float(v.x << 16);
  f[1] = __uint_as_float(v.x & 0xFFFF0000u);
  f[2] = __uint_as_float(v.y << 16);
  f[3] = __uint_as_float(v.y & 0xFFFF0000u);
  f[4] = __uint_as_float(v.z << 16);
  f[5] = __uint_as_float(v.z & 0xFFFF0000u);
  f[6] = __uint_as_float(v.w << 16);
  f[7] = __uint_as_float(v.w & 0xFFFF0000u);
}

// ---------------------------------------------------------------------------
// K-split fp32 GEMM: out[m][j] (+=) sum_c W[m][c] * X[c][j], M x 128, K=2048
// MODE 0: W rows 0..2047 wq, 2048..2303 wk, 2304..2559 wv; X = x (B,HID,1,S)
// MODE 1: W = wo; X = A2 ws [2048][128]; out scattered to (B,HID,1,S)
// grid: (M/64, 8), block 256. KC=256 per block, atomicAdd into zeroed out.
// ---------------------------------------------------------------------------
template<int MODE>
__global__ __launch_bounds__(256) void gemm_ksplit(
    const float* __restrict__ w0, const float* __restrict__ w1,
    const float* __restrict__ w2, const float* __restrict__ X,
    float* __restrict__ outp)
{
  __shared__ float Ws[64 * 68];    // pad 68: conflict-free f4 reads
  __shared__ float Xs[64 * 132];   // pad 132
  const int tid = threadIdx.x;
  const int m0 = blockIdx.x * 64;
  const int kc0 = blockIdx.y * 256;
  const float* wbase;
  if (MODE == 0) {
    if (m0 < 2048) wbase = w0 + (size_t)m0 * 2048;
    else if (m0 < 2304) wbase = w1 + (size_t)(m0 - 2048) * 2048;
    else wbase = w2 + (size_t)(m0 - 2304) * 2048;
  } else {
    wbase = w0 + (size_t)m0 * 2048;
  }
  const int tm = tid & 7;
  const int tn = tid >> 3;   // 0..31
  float acc[8][4];
#pragma unroll
  for (int i = 0; i < 8; ++i)
#pragma unroll
    for (int j = 0; j < 4; ++j) acc[i][j] = 0.0f;

  for (int kk = 0; kk < 256; kk += 64) {
    const int c0 = kc0 + kk;
    // stage W 64x64
    for (int i = tid; i < 1024; i += 256) {
      int r = i >> 4, cq = i & 15;
      float4 w4 = *(const float4*)(wbase + (size_t)r * 2048 + c0 + cq * 4);
      *(float4*)(&Ws[r * 68 + cq * 4]) = w4;
    }
    // stage X 64x128
    for (int i = tid; i < 2048; i += 256) {
      int c = i >> 5, jq = i & 31;
      int ch = c0 + c;
      float4 x4;
      if (MODE == 0) {
        int bb = jq >> 2;           // batch of column j=4*jq
        int ss = (jq & 3) * 4;      // s within batch
        x4 = *(const float4*)(X + ((size_t)bb * 2048 + ch) * 16 + ss);
      } else {
        x4 = *(const float4*)(X + (size_t)ch * 128 + jq * 4);
      }
      *(float4*)(&Xs[c * 132 + jq * 4]) = x4;
    }
    __syncthreads();
#pragma unroll 4
    for (int dd4 = 0; dd4 < 16; ++dd4) {
      float4 w4[8];
#pragma unroll
      for (int i = 0; i < 8; ++i)
        w4[i] = *(const float4*)(&Ws[(tm + 8 * i) * 68 + dd4 * 4]);
#pragma unroll
      for (int e = 0; e < 4; ++e) {
        float xr[4];
#pragma unroll
        for (int j = 0; j < 4; ++j) xr[j] = Xs[(dd4 * 4 + e) * 132 + tn + 32 * j];
#pragma unroll
        for (int i = 0; i < 8; ++i) {
          float we = (e == 0) ? w4[i].x : (e == 1) ? w4[i].y
                     : (e == 2) ? w4[i].z : w4[i].w;
#pragma unroll
          for (int j = 0; j < 4; ++j) acc[i][j] = fmaf(we, xr[j], acc[i][j]);
        }
      }
    }
    __syncthreads();
  }
#pragma unroll
  for (int i = 0; i < 8; ++i) {
    int m = m0 + tm + 8 * i;
#pragma unroll
    for (int j = 0; j < 4; ++j) {
      int jj = tn + 32 * j;
      if (MODE == 0) {
        atomicAdd(&outp[(size_t)m * 128 + jj], acc[i][j]);
      } else {
        atomicAdd(&outp[(size_t)(jj >> 4) * 32768 + m * 16 + (jj & 15)], acc[i][j]);
      }
    }
  }
}

// ---------------------------------------------------------------------------
// RMSNorm + rotary. One wave per (row of q/k/v). 2560 waves.
//  waves 0..2047   : q -> Qa [b][h][s][d], pre-scaled by 1/sqrt(D)
//  waves 2048..2303: k -> knew ws [b][kvh][s][d]
//  waves 2304..2559: v -> vnew ws [b][kvh][s][d] (plain copy)
// ---------------------------------------------------------------------------
__global__ __launch_bounds__(256) void norm_rot(
    const float* __restrict__ qkv, const float* __restrict__ cosb,
    const float* __restrict__ sinb, const float* __restrict__ qw,
    const float* __restrict__ kw,
    float* __restrict__ Qa, float* __restrict__ knew, float* __restrict__ vnew)
{
  const int wid = blockIdx.x * 4 + (threadIdx.x >> 6);
  const int lane = threadIdx.x & 63;
  const float SCALE = 0.08838834764831845f;  // 1/sqrt(128)
  if (wid < 2048) {                 // q
    int b = wid >> 8, h = (wid >> 4) & 15, s = wid & 15;
    int j = b * 16 + s;
    float v1 = qkv[(size_t)(h * 128 + lane) * 128 + j];
    float v2 = qkv[(size_t)(h * 128 + lane + 64) * 128 + j];
    float ss = v1 * v1 + v2 * v2;
#pragma unroll
    for (int o = 32; o > 0; o >>= 1) ss += __shfl_xor(ss, o, 64);
    float rr = rsqrtf(ss * (1.0f / 128.0f) + 1e-6f);
    float n1 = v1 * rr * qw[lane];
    float n2 = v2 * rr * qw[lane + 64];
    float c = cosb[s * 64 + lane], sn = sinb[s * 64 + lane];
    float* dst = Qa + (size_t)((b * 16 + h) * 16 + s) * 128;
    dst[lane]      = (n1 * c - n2 * sn) * SCALE;
    dst[lane + 64] = (n2 * c + n1 * sn) * SCALE;
  } else if (wid < 2304) {          // k
    int idx = wid - 2048;
    int b = idx >> 5, kvh = (idx >> 4) & 1, s = idx & 15;
    int j = b * 16 + s;
    int row = 2048 + kvh * 128;
    float v1 = qkv[(size_t)(row + lane) * 128 + j];
    float v2 = qkv[(size_t)(row + lane + 64) * 128 + j];
    float ss = v1 * v1 + v2 * v2;
#pragma unroll
    for (int o = 32; o > 0; o >>= 1) ss += __shfl_xor(ss, o, 64);
    float rr = rsqrtf(ss * (1.0f / 128.0f) + 1e-6f);
    float n1 = v1 * rr * kw[lane];
    float n2 = v2 * rr * kw[lane + 64];
    float c = cosb[s * 64 + lane], sn = sinb[s * 64 + lane];
    float* dst = knew + (size_t)((b * 2 + kvh) * 16 + s) * 128;
    dst[lane]      = n1 * c - n2 * sn;
    dst[lane + 64] = n2 * c + n1 * sn;
  } else {                          // v (no norm, no rotary)
    int idx = wid - 2304;
    int b = idx >> 5, kvh = (idx >> 4) & 1, s = idx & 15;
    int j = b * 16 + s;
    int row = 2304 + kvh * 128;
    float v1 = qkv[(size_t)(row + lane) * 128 + j];
    float v2 = qkv[(size_t)(row + lane + 64) * 128 + j];
    float* dst = vnew + (size_t)((b * 2 + kvh) * 16 + s) * 128;
    dst[lane]      = v1;
    dst[lane + 64] = v2;
  }
}

// ---------------------------------------------------------------------------
// Flash attention with fused KV-cache copy-out.
// grid 512 = (b[8], kvh[2], gh[2], chunk[16]); block 256.
// Block: 64 q-rows (gh half: heads g=gh*4..gh*4+3, s=0..15) x 512 keys.
// LDS: Qs/KVs bf16 XOR-swizzled, Ps fp32 rotate-swizzled; 49.4 KB total.
// Per-row m/l live in registers of threads 0..63.
// gh==0 blocks also write the staged K/V tiles to new_k/new_v (cache copy),
// substituting rows [pos,pos+16) from knew/vnew.
// ---------------------------------------------------------------------------
__global__ __launch_bounds__(256) void attn_kernel(
    const float* __restrict__ Qa,
    const float* __restrict__ kcache, const float* __restrict__ vcache,
    const float* __restrict__ knew, const float* __restrict__ vnew,
    const int* __restrict__ posp, const float* __restrict__ mask,
    float* __restrict__ outk, float* __restrict__ outv,
    float* __restrict__ Opart, float* __restrict__ Mpart, float* __restrict__ Lpart)
{
  __shared__ __align__(16) unsigned short Qs[64 * 128];
  __shared__ __align__(16) unsigned short KVs[64 * 128];
  __shared__ float Ps[64 * 64];
  __shared__ float alpha_s[64];

  const int tid = threadIdx.x;
  const int bid = blockIdx.x;
  const int b = bid >> 6, kvh = (bid >> 5) & 1, gh = (bid >> 4) & 1, chunk = bid & 15;
  const int pos = *posp;
  const int bk = b * 2 + kvh;

  // ---- stage Q (64 rows x 128 d), bf16, swizzled: chunk col = (d>>3) ^ (r&15)
  const float* Qbase = Qa + (size_t)(b * 256 + kvh * 128 + gh * 64) * 128;
  for (int i = tid; i < 2048; i += 256) {       // float4 granules
    int r = i >> 5, g = i & 31;
    float4 q4 = *(const float4*)(Qbase + r * 128 + g * 4);
    ushort4 u;
    u.x = f2bf(q4.x); u.y = f2bf(q4.y); u.z = f2bf(q4.z); u.w = f2bf(q4.w);
    int off = r * 128 + (((g >> 1) ^ (r & 15)) << 3) + ((g & 1) << 2);
    *(ushort4*)(&Qs[off]) = u;
  }

  float m_reg = -INFINITY, l_reg = 0.0f;        // valid for tid<64 (row tid)
  float oacc[4][8];
#pragma unroll
  for (int i = 0; i < 4; ++i)
#pragma unroll
    for (int j = 0; j < 8; ++j) oacc[i][j] = 0.0f;

  const int tr = tid & 15, tc = tid >> 4;       // thread tile coords

  for (int tile = 0; tile < 8; ++tile) {
    const int t0 = chunk * 512 + tile * 64;
    // ---- stage K tile (+ cache copy-out by gh==0)
    for (int i = tid; i < 2048; i += 256) {
      int tl = i >> 5, g = i & 31;
      int tg = t0 + tl;
      const float* src = (tg >= pos && tg < pos + 16)
          ? (knew + (size_t)(bk * 16 + (tg - pos)) * 128)
          : (kcache + ((size_t)bk * 8192 + tg) * 128);
      float4 k4 = *(const float4*)(src + g * 4);
      if (gh == 0)
        *(float4*)(outk + ((size_t)bk * 8192 + tg) * 128 + g * 4) = k4;
      ushort4 u;
      u.x = f2bf(k4.x); u.y = f2bf(k4.y); u.z = f2bf(k4.z); u.w = f2bf(k4.w);
      int off = tl * 128 + (((g >> 1) ^ (tl & 15)) << 3) + ((g & 1) << 2);
      *(ushort4*)(&KVs[off]) = u;
    }
    __syncthreads();

    // ---- scores: 64x64 tile, micro 4x4 per thread
    float sc[4][4];
#pragma unroll
    for (int i = 0; i < 4; ++i)
#pragma unroll
      for (int j = 0; j < 4; ++j) sc[i][j] = 0.0f;
#pragma unroll 2
    for (int dd8 = 0; dd8 < 16; ++dd8) {
      float qf[4][8], kf[4][8];
#pragma unroll
      for (int i = 0; i < 4; ++i) {
        int r = tr + 16 * i;
        uint4 qv = *(const uint4*)(&Qs[r * 128 + ((dd8 ^ tr) << 3)]);
        unpack8(qv, qf[i]);
      }
#pragma unroll
      for (int j = 0; j < 4; ++j) {
        int cr = tc + 16 * j;
        uint4 kv = *(const uint4*)(&KVs[cr * 128 + ((dd8 ^ tc) << 3)]);
        unpack8(kv, kf[j]);
      }
#pragma unroll
      for (int e = 0; e < 8; ++e)
#pragma unroll
        for (int i = 0; i < 4; ++i)
#pragma unroll
          for (int j = 0; j < 4; ++j)
            sc[i][j] = fmaf(qf[i][e], kf[j][e], sc[i][j]);
    }
    // write raw scores to Ps (rotate-swizzled columns)
#pragma unroll
    for (int i = 0; i < 4; ++i) {
      int r = tr + 16 * i;
#pragma unroll
      for (int j = 0; j < 4; ++j) {
        int t = tc + 16 * j;
        Ps[r * 64 + ((t + r) & 63)] = sc[i][j];
      }
    }
    __syncthreads();

    if (tid < 64) {
      // ---- online softmax for row tid
      int r = tid, s = r & 15;
      const float* mrow = mask + (size_t)s * 8192 + t0;
      float mx = -INFINITY;
      for (int t = 0; t < 64; ++t) {
        float v = Ps[r * 64 + ((t + r) & 63)] + mrow[t];
        mx = fmaxf(mx, v);
      }
      float m_new = fmaxf(m_reg, mx);
      float al = expf(m_reg - m_new);           // first tile: exp(-inf)=0
      float lsum = 0.0f;
      for (int t = 0; t < 64; ++t) {
        int a = r * 64 + ((t + r) & 63);
        float p = expf(Ps[a] + mrow[t] - m_new);
        Ps[a] = p;
        lsum += p;
      }
      m_reg = m_new;
      l_reg = l_reg * al + lsum;
      alpha_s[r] = al;
    } else {
      // ---- stage V tile (threads 64..255) (+ cache copy-out by gh==0)
      for (int i = tid - 64; i < 2048; i += 192) {
        int tl = i >> 5, g = i & 31;
        int tg = t0 + tl;
        const float* src = (tg >= pos && tg < pos + 16)
            ? (vnew + (size_t)(bk * 16 + (tg - pos)) * 128)
            : (vcache + ((size_t)bk * 8192 + tg) * 128);
        float4 v4 = *(const float4*)(src + g * 4);
        if (gh == 0)
          *(float4*)(outv + ((size_t)bk * 8192 + tg) * 128 + g * 4) = v4;
        ushort4 u;
        u.x = f2bf(v4.x); u.y = f2bf(v4.y); u.z = f2bf(v4.z); u.w = f2bf(v4.w);
        int off = tl * 128 + (((g >> 1) ^ (tl & 15)) << 3) + ((g & 1) << 2);
        *(ushort4*)(&KVs[off]) = u;
      }
    }
    __syncthreads();

    // ---- O = O*alpha + P @ V : micro 4 rows x 8 d-cols per thread
    {
#pragma unroll
      for (int i = 0; i < 4; ++i) {
        float al = alpha_s[tr + 16 * i];
#pragma unroll
        for (int j = 0; j < 8; ++j) oacc[i][j] *= al;
      }
      for (int t = 0; t < 64; ++t) {
        float pv[4];
#pragma unroll
        for (int i = 0; i < 4; ++i) {
          int r = tr + 16 * i;
          pv[i] = Ps[r * 64 + ((t + r) & 63)];
        }
        float vf[8];
#pragma unroll
        for (int j = 0; j < 8; ++j) {
          int d = tc + 16 * j;
          int off = t * 128 + ((((d >> 3) ^ (t & 15))) << 3) + (d & 7);
          vf[j] = bf2f(KVs[off]);
        }
#pragma unroll
        for (int i = 0; i < 4; ++i)
#pragma unroll
          for (int j = 0; j < 8; ++j)
            oacc[i][j] = fmaf(pv[i], vf[j], oacc[i][j]);
      }
    }
    __syncthreads();
  }

  // ---- write partials
  const size_t obase = ((size_t)(bk * 16 + chunk) * 128 + gh * 64) * 128;
#pragma unroll
  for (int i = 0; i < 4; ++i) {
    int r = tr + 16 * i;
#pragma unroll
    for (int j = 0; j < 8; ++j) {
      int d = tc + 16 * j;
      Opart[obase + (size_t)r * 128 + d] = oacc[i][j];
    }
  }
  if (tid < 64) {
    int idx = (bk * 16 + chunk) * 128 + gh * 64 + tid;
    Mpart[idx] = m_reg;
    Lpart[idx] = l_reg;
  }
}

// ---------------------------------------------------------------------------
// Combine 16 chunk-partials per row; write A2 [c=h*128+d][j=b*16+s] for GEMM.
// One wave per (b,kvh,r) row; 2048 waves.
// ---------------------------------------------------------------------------
__global__ __launch_bounds__(256) void combine_kernel(
    const float* __restrict__ Opart, const float* __restrict__ Mpart,
    const float* __restrict__ Lpart, float* __restrict__ A2)
{
  const int wid = blockIdx.x * 4 + (threadIdx.x >> 6);
  const int lane = threadIdx.x & 63;
  const int b = wid >> 8, kvh = (wid >> 7) & 1, r = wid & 127;
  const int bk = b * 2 + kvh;
  float mc[16], lc[16];
  float M = -INFINITY;
#pragma unroll
  for (int c = 0; c < 16; ++c) {
    mc[c] = Mpart[(bk * 16 + c) * 128 + r];
    lc[c] = Lpart[(bk * 16 + c) * 128 + r];
    M = fmaxf(M, mc[c]);
  }
  float L = 0.0f, wgt[16];
#pragma unroll
  for (int c = 0; c < 16; ++c) {
    wgt[c] = expf(mc[c] - M);
    L += wgt[c] * lc[c];
  }
  float inv = 1.0f / L;
  const int h = kvh * 8 + (r >> 4), s = r & 15;
#pragma unroll
  for (int dh = 0; dh < 2; ++dh) {
    int d = lane + dh * 64;
    float o = 0.0f;
#pragma unroll
    for (int c = 0; c < 16; ++c)
      o = fmaf(wgt[c], Opart[((size_t)(bk * 16 + c) * 128 + r) * 128 + d], o);
    A2[(size_t)(h * 128 + d) * 128 + (b * 16 + s)] = o * inv;
  }
}

// ---------------------------------------------------------------------------
extern "C" void kernel_launch(void* const* d_in, const int* in_sizes, int n_in,
                              void* d_out, int out_size, void* d_ws, size_t ws_size,
                              hipStream_t stream) {
  const float* x    = (const float*)d_in[0];
  const float* cosb = (const float*)d_in[1];
  const float* sinb = (const float*)d_in[2];
  const float* kc   = (const float*)d_in[3];
  const float* vc   = (const float*)d_in[4];
  const int*   posp = (const int*)d_in[5];
  const float* mask = (const float*)d_in[6];
  const float* wq   = (const float*)d_in[7];
  const float* wk   = (const float*)d_in[8];
  const float* wv   = (const float*)d_in[9];
  const float* wo   = (const float*)d_in[10];
  const float* qw   = (const float*)d_in[11];
  const float* kw   = (const float*)d_in[12];

  float* out  = (float*)d_out;
  float* outk = out + 262144;
  float* outv = outk + 16777216;

  float* ws      = (float*)d_ws;
  float* ws_qkv  = ws;            // 327,680  [2560][128]
  float* ws_knew = ws + 327680;   // 32,768   [B][KVH][S][D]
  float* ws_vnew = ws + 360448;   // 32,768
  float* ws_Qa   = ws + 393216;   // 262,144  [B][H][S][D]
  float* ws_A2   = ws + 655360;   // 262,144  [2048][128]
  float* ws_M    = ws + 917504;   // 32,768
  float* ws_L    = ws + 950272;   // 32,768
  float* ws_O    = ws + 983040;   // 4,194,304

  hipMemsetAsync(ws_qkv, 0, (size_t)327680 * 4, stream);
  hipMemsetAsync(out, 0, (size_t)262144 * 4, stream);

  gemm_ksplit<0><<<dim3(40, 8), 256, 0, stream>>>(wq, wk, wv, x, ws_qkv);
  norm_rot<<<640, 256, 0, stream>>>(ws_qkv, cosb, sinb, qw, kw,
                                    ws_Qa, ws_knew, ws_vnew);
  attn_kernel<<<512, 256, 0, stream>>>(ws_Qa, kc, vc, ws_knew, ws_vnew,
                                       posp, mask, outk, outv,
                                       ws_O, ws_M, ws_L);
  combine_kernel<<<512, 256, 0, stream>>>(ws_O, ws_M, ws_L, ws_A2);
  gemm_ksplit<1><<<dim3(32, 8), 256, 0, stream>>>(wo, wo, wo, ws_A2, out);
}

// Round 3
// 346.928 us; speedup vs baseline: 2.4655x; 2.4655x over previous
//
#include <hip/hip_runtime.h>
#include <cstdint>
#include <cstddef>

// B=8 H=16 KVH=2 D=128 S=16 T=8192 HID=2048, G=8
// d_out = [out 262144][new_k 16777216][new_v 16777216] fp32

typedef __attribute__((ext_vector_type(8))) short bf16x8;
typedef __attribute__((ext_vector_type(4))) float f32x4;
typedef unsigned short u16;
typedef unsigned int u32;

#define MFMA16(a, b, c) __builtin_amdgcn_mfma_f32_16x16x32_bf16(a, b, c, 0, 0, 0)

static __device__ __forceinline__ u16 f2bf(float f) {
  u32 u = __float_as_uint(f);
  u += 0x7FFFu + ((u >> 16) & 1u);   // RNE
  return (u16)(u >> 16);
}
static __device__ __forceinline__ float bf2f(u16 u) {
  return __uint_as_float(((u32)u) << 16);
}
static __device__ __forceinline__ u32 pk2(float a, float b) {
  return (u32)f2bf(a) | ((u32)f2bf(b) << 16);
}

// ---------------------------------------------------------------------------
// x [8][2048][1][16] f32 -> Xt bf16 [j=b*16+s][c] (row-major, 2048 cols)
// ---------------------------------------------------------------------------
__global__ __launch_bounds__(256) void transpose_x(const float* __restrict__ x,
                                                   u16* __restrict__ Xt) {
  int id = blockIdx.x * 256 + threadIdx.x;           // 65536 total
  int b = id >> 13, c = (id >> 2) & 2047, s4 = id & 3;
  float4 v = *(const float4*)(x + ((size_t)(b * 2048 + c)) * 16 + s4 * 4);
  size_t base = (size_t)(b * 16 + s4 * 4) * 2048 + c;
  Xt[base]        = f2bf(v.x);
  Xt[base + 2048] = f2bf(v.y);
  Xt[base + 4096] = f2bf(v.z);
  Xt[base + 6144] = f2bf(v.w);
}

// ---------------------------------------------------------------------------
// GEMM: D[m][j] = sum_c W[m][c] * Bt[j][c],  K=2048, N=128, M-tile=16, full K.
// MODE 0: W = concat(wq,wk,wv) rows; store qkv[m*128+j] f32.
// MODE 1: W = wo; store out[(j>>4)*32768 + m*16 + (j&15)] f32.
// grid.x = M/16; block 256.
// ---------------------------------------------------------------------------
template <int MODE>
__global__ __launch_bounds__(256) void gemm16(const float* __restrict__ w0,
                                              const float* __restrict__ w1,
                                              const float* __restrict__ w2,
                                              const u16* __restrict__ Bt,
                                              float* __restrict__ outp) {
  __shared__ __align__(16) u16 sW[16 * 256];  // 8 KB, granule-rotated
  const int tid = threadIdx.x, lane = tid & 63, w = tid >> 6;
  const int q = lane >> 4, n = lane & 15;
  const int m0 = blockIdx.x * 16;
  const float* wbase;
  if (MODE == 0) {
    if (m0 < 2048)      wbase = w0 + (size_t)m0 * 2048;
    else if (m0 < 2304) wbase = w1 + (size_t)(m0 - 2048) * 2048;
    else                wbase = w2 + (size_t)(m0 - 2304) * 2048;
  } else {
    wbase = w0 + (size_t)m0 * 2048;
  }
  f32x4 acc0 = {0.f, 0.f, 0.f, 0.f}, acc1 = acc0;

  for (int c0 = 0; c0 < 2048; c0 += 256) {
    {  // stage W tile 16x256 -> bf16, granule-rotated
      int m = tid >> 4, s16 = tid & 15;
      const float* src = wbase + (size_t)m * 2048 + c0 + s16 * 16;
      float4 a = *(const float4*)(src);
      float4 b = *(const float4*)(src + 4);
      float4 c = *(const float4*)(src + 8);
      float4 d = *(const float4*)(src + 12);
      uint4 u0 = {pk2(a.x, a.y), pk2(a.z, a.w), pk2(b.x, b.y), pk2(b.z, b.w)};
      uint4 u1 = {pk2(c.x, c.y), pk2(c.z, c.w), pk2(d.x, d.y), pk2(d.z, d.w)};
      int G0 = 2 * s16;
      *(uint4*)&sW[m * 256 + ((G0 + m) & 31) * 8]     = u0;
      *(uint4*)&sW[m * 256 + ((G0 + 1 + m) & 31) * 8] = u1;
    }
    __syncthreads();
    // B-fragments straight from global (Bt is small, L2-resident)
    bf16x8 bfr[2][8];
#pragma unroll
    for (int e = 0; e < 2; ++e) {
      int j = 32 * w + 16 * e + n;
      const u16* bp = Bt + (size_t)j * 2048 + c0 + q * 8;
#pragma unroll
      for (int ks = 0; ks < 8; ++ks) bfr[e][ks] = *(const bf16x8*)(bp + ks * 32);
    }
#pragma unroll
    for (int ks = 0; ks < 8; ++ks) {
      bf16x8 af = *(const bf16x8*)&sW[n * 256 + (((4 * ks + q) + n) & 31) * 8];
      acc0 = MFMA16(af, bfr[0][ks], acc0);
      acc1 = MFMA16(af, bfr[1][ks], acc1);
    }
    __syncthreads();
  }
#pragma unroll
  for (int e = 0; e < 2; ++e) {
    f32x4 a = e ? acc1 : acc0;
    int j = 32 * w + 16 * e + n;
#pragma unroll
    for (int reg = 0; reg < 4; ++reg) {
      int m = m0 + 4 * q + reg;
      if (MODE == 0) outp[(size_t)m * 128 + j] = a[reg];
      else outp[(size_t)(j >> 4) * 32768 + m * 16 + (j & 15)] = a[reg];
    }
  }
}

// ---------------------------------------------------------------------------
// RMSNorm + rotary. One wave per row; 2560 waves.
//  0..2047   : q -> Qa bf16 [b][h][s][d], pre-scaled by 1/sqrt(D)
//  2048..2303: k -> knew f32; 2304..2559: v -> vnew f32 (copy)
// ---------------------------------------------------------------------------
__global__ __launch_bounds__(256) void norm_rot(
    const float* __restrict__ qkv, const float* __restrict__ cosb,
    const float* __restrict__ sinb, const float* __restrict__ qw,
    const float* __restrict__ kw,
    u16* __restrict__ Qa, float* __restrict__ knew, float* __restrict__ vnew) {
  const int wid = blockIdx.x * 4 + (threadIdx.x >> 6);
  const int lane = threadIdx.x & 63;
  const float SCALE = 0.08838834764831845f;  // 1/sqrt(128)
  if (wid < 2048) {
    int b = wid >> 8, h = (wid >> 4) & 15, s = wid & 15;
    int j = b * 16 + s;
    float v1 = qkv[(size_t)(h * 128 + lane) * 128 + j];
    float v2 = qkv[(size_t)(h * 128 + lane + 64) * 128 + j];
    float ss = v1 * v1 + v2 * v2;
#pragma unroll
    for (int o = 32; o > 0; o >>= 1) ss += __shfl_xor(ss, o, 64);
    float rr = rsqrtf(ss * (1.0f / 128.0f) + 1e-6f);
    float n1 = v1 * rr * qw[lane];
    float n2 = v2 * rr * qw[lane + 64];
    float c = cosb[s * 64 + lane], sn = sinb[s * 64 + lane];
    u16* dst = Qa + (size_t)((b * 16 + h) * 16 + s) * 128;
    dst[lane]      = f2bf((n1 * c - n2 * sn) * SCALE);
    dst[lane + 64] = f2bf((n2 * c + n1 * sn) * SCALE);
  } else if (wid < 2304) {
    int idx = wid - 2048;
    int b = idx >> 5, kvh = (idx >> 4) & 1, s = idx & 15;
    int j = b * 16 + s;
    int row = 2048 + kvh * 128;
    float v1 = qkv[(size_t)(row + lane) * 128 + j];
    float v2 = qkv[(size_t)(row + lane + 64) * 128 + j];
    float ss = v1 * v1 + v2 * v2;
#pragma unroll
    for (int o = 32; o > 0; o >>= 1) ss += __shfl_xor(ss, o, 64);
    float rr = rsqrtf(ss * (1.0f / 128.0f) + 1e-6f);
    float n1 = v1 * rr * kw[lane];
    float n2 = v2 * rr * kw[lane + 64];
    float c = cosb[s * 64 + lane], sn = sinb[s * 64 + lane];
    float* dst = knew + (size_t)((b * 2 + kvh) * 16 + s) * 128;
    dst[lane]      = n1 * c - n2 * sn;
    dst[lane + 64] = n2 * c + n1 * sn;
  } else {
    int idx = wid - 2304;
    int b = idx >> 5, kvh = (idx >> 4) & 1, s = idx & 15;
    int j = b * 16 + s;
    int row = 2304 + kvh * 128;
    float* dst = vnew + (size_t)((b * 2 + kvh) * 16 + s) * 128;
    dst[lane]      = qkv[(size_t)(row + lane) * 128 + j];
    dst[lane + 64] = qkv[(size_t)(row + lane + 64) * 128 + j];
  }
}

// ---------------------------------------------------------------------------
// Flash attention, MFMA. grid 512 = bk(16) x chunk(32 of 256 keys); block 256.
// Per block: 128 q-rows x 256 keys (4 tiles of 64). S^T = K·Q^T (no transposes),
// V transposed via MFMA-by-identity, P via contiguous ushort4 from C-layout.
// LDS: sQ 32KB (Q then K|V natural), sP 16KB, sVt 16KB = 64KB exactly.
// ---------------------------------------------------------------------------
__global__ __launch_bounds__(256, 2) void attn(
    const u16* __restrict__ Qa, const float* __restrict__ kcache,
    const float* __restrict__ vcache, const float* __restrict__ knew,
    const float* __restrict__ vnew, const int* __restrict__ posp,
    const float* __restrict__ mask, float* __restrict__ outk,
    float* __restrict__ outv, u16* __restrict__ Opart,
    float* __restrict__ Mpart, float* __restrict__ Lpart) {
  __shared__ __align__(16) u16 sQ[16384];  // 32 KB: Q[128][128]; later K|V (8192 each)
  __shared__ __align__(16) u16 sP[8192];   // P[r(128)][t(64)] granule-rotated
  __shared__ __align__(16) u16 sVt[8192];  // Vt[d(128)][t(64)] granule-rotated

  const int tid = threadIdx.x, lane = tid & 63, w = tid >> 6;
  const int q = lane >> 4, n = lane & 15;
  const int bid = blockIdx.x;
  const int bk = bid >> 5, chunk = bid & 31;
  const int b = bk >> 1, kvh = bk & 1;
  const int pos = *posp;

  // ---- stage Q (bf16 global -> LDS, granule-rotated), preload B-frags
  for (int i = tid; i < 2048; i += 256) {
    int r = i >> 4, g = i & 15;
    int h = kvh * 8 + (r >> 4), s = r & 15;
    uint4 v = *(const uint4*)(Qa + (size_t)((b * 16 + h) * 16 + s) * 128 + g * 8);
    *(uint4*)&sQ[r * 128 + ((g + r) & 15) * 8] = v;
  }
  __syncthreads();
  bf16x8 qf[2][4];
#pragma unroll
  for (int e = 0; e < 2; ++e) {
    int r = 32 * w + 16 * e + n;
#pragma unroll
    for (int ks = 0; ks < 4; ++ks)
      qf[e][ks] = *(const bf16x8*)&sQ[r * 128 + (((4 * ks + q) + r) & 15) * 8];
  }
  __syncthreads();

  // identity B-frags for MFMA transpose (one-hot bf16 1.0)
  bf16x8 idE = {0, 0, 0, 0, 0, 0, 0, 0}, idO = idE;
  {
    const short one = (short)0x3F80;
    int tq = n >> 3, te = n & 7;
#pragma unroll
    for (int e = 0; e < 8; ++e) {
      if (q == tq && e == te) idE[e] = one;
      if (q == tq + 2 && e == te) idO[e] = one;
    }
  }

  float m_old[2] = {-INFINITY, -INFINITY}, l_old[2] = {0.f, 0.f};
  f32x4 oacc[2][8];
#pragma unroll
  for (int e = 0; e < 2; ++e)
#pragma unroll
    for (int nt = 0; nt < 8; ++nt) oacc[e][nt] = (f32x4){0.f, 0.f, 0.f, 0.f};

  for (int tile = 0; tile < 4; ++tile) {
    const int t0 = chunk * 256 + tile * 64;
    // ---- stage K,V natural bf16 (+ fused cache copy + new-row substitution)
    for (int i = tid; i < 2048; i += 256) {
      int isV = i >> 10;
      int tl = (i >> 4) & 63, g = i & 15;
      int tg = t0 + tl;
      const float* src;
      float* dst;
      if (!isV) {
        src = (tg >= pos && tg < pos + 16)
                  ? (knew + (size_t)(bk * 16 + (tg - pos)) * 128)
                  : (kcache + ((size_t)bk * 8192 + tg) * 128);
        dst = outk + ((size_t)bk * 8192 + tg) * 128;
      } else {
        src = (tg >= pos && tg < pos + 16)
                  ? (vnew + (size_t)(bk * 16 + (tg - pos)) * 128)
                  : (vcache + ((size_t)bk * 8192 + tg) * 128);
        dst = outv + ((size_t)bk * 8192 + tg) * 128;
      }
      float4 a = *(const float4*)(src + g * 8);
      float4 b2 = *(const float4*)(src + g * 8 + 4);
      *(float4*)(dst + g * 8) = a;
      *(float4*)(dst + g * 8 + 4) = b2;
      uint4 u = {pk2(a.x, a.y), pk2(a.z, a.w), pk2(b2.x, b2.y), pk2(b2.z, b2.w)};
      *(uint4*)&sQ[isV * 8192 + tl * 128 + ((g + tl) & 15) * 8] = u;
    }
    // mask values for this lane's S entries (s = n)
    float mv[4][4];
#pragma unroll
    for (int mt = 0; mt < 4; ++mt)
#pragma unroll
      for (int rg = 0; rg < 4; ++rg)
        mv[mt][rg] = mask[(size_t)n * 8192 + t0 + 16 * mt + 4 * q + rg];
    __syncthreads();  // A

    // ---- S^T = K·Q^T
    f32x4 sacc[4][2];
#pragma unroll
    for (int mt = 0; mt < 4; ++mt) {
      sacc[mt][0] = (f32x4){0.f, 0.f, 0.f, 0.f};
      sacc[mt][1] = sacc[mt][0];
    }
#pragma unroll
    for (int ks = 0; ks < 4; ++ks) {
#pragma unroll
      for (int mt = 0; mt < 4; ++mt) {
        int trow = 16 * mt + n;
        bf16x8 kf = *(const bf16x8*)&sQ[trow * 128 + (((4 * ks + q) + trow) & 15) * 8];
        sacc[mt][0] = MFMA16(kf, qf[0][ks], sacc[mt][0]);
        sacc[mt][1] = MFMA16(kf, qf[1][ks], sacc[mt][1]);
      }
    }

    // ---- V transpose via MFMA identity: Vt[d][t], wave w does d in [32w,32w+32)
#pragma unroll
    for (int mtv = 0; mtv < 4; ++mtv) {
      int trow = 16 * mtv + n;
      bf16x8 vfr = *(const bf16x8*)&sQ[8192 + trow * 128 + (((4 * w + q) + trow) & 15) * 8];
      f32x4 z = {0.f, 0.f, 0.f, 0.f};
      f32x4 d0 = MFMA16(vfr, idE, z);
      f32x4 d1 = MFMA16(vfr, idO, z);
      int G = 2 * mtv + (q >> 1), off = 4 * (q & 1);
      int dp0 = 32 * w + n, dp1 = dp0 + 16;
      uint2 u0 = {pk2(d0[0], d0[1]), pk2(d0[2], d0[3])};
      uint2 u1 = {pk2(d1[0], d1[1]), pk2(d1[2], d1[3])};
      *(uint2*)&sVt[dp0 * 64 + ((G + dp0) & 7) * 8 + off] = u0;
      *(uint2*)&sVt[dp1 * 64 + ((G + dp1) & 7) * 8 + off] = u1;
    }

    // ---- online softmax (in-register, rows r = 32w+16e+n) + write P
    float al[2];
#pragma unroll
    for (int e = 0; e < 2; ++e) {
      float sv[4][4];
      float mx = -INFINITY;
#pragma unroll
      for (int mt = 0; mt < 4; ++mt)
#pragma unroll
        for (int rg = 0; rg < 4; ++rg) {
          float v = sacc[mt][e][rg] + mv[mt][rg];
          sv[mt][rg] = v;
          mx = fmaxf(mx, v);
        }
      mx = fmaxf(mx, __shfl_xor(mx, 16));
      mx = fmaxf(mx, __shfl_xor(mx, 32));
      float mn = fmaxf(m_old[e], mx);
      al[e] = __expf(m_old[e] - mn);
      float ts = 0.f;
      int r = 32 * w + 16 * e + n;
#pragma unroll
      for (int mt = 0; mt < 4; ++mt) {
        float p0 = __expf(sv[mt][0] - mn), p1 = __expf(sv[mt][1] - mn);
        float p2 = __expf(sv[mt][2] - mn), p3 = __expf(sv[mt][3] - mn);
        ts += (p0 + p1) + (p2 + p3);
        uint2 up = {pk2(p0, p1), pk2(p2, p3)};
        int G = 2 * mt + (q >> 1), off = 4 * (q & 1);
        *(uint2*)&sP[r * 64 + ((G + r) & 7) * 8 + off] = up;
      }
      ts += __shfl_xor(ts, 16);
      ts += __shfl_xor(ts, 32);
      l_old[e] = l_old[e] * al[e] + ts;
      m_old[e] = mn;
    }
    __syncthreads();  // B

    // ---- O rescale (alpha via in-wave shuffle) + PV
#pragma unroll
    for (int e = 0; e < 2; ++e) {
      float an[4];
#pragma unroll
      for (int rg = 0; rg < 4; ++rg) an[rg] = __shfl(al[e], 4 * q + rg);
#pragma unroll
      for (int nt = 0; nt < 8; ++nt)
#pragma unroll
        for (int rg = 0; rg < 4; ++rg) oacc[e][nt][rg] *= an[rg];
    }
    bf16x8 Pf[2][2];
#pragma unroll
    for (int e = 0; e < 2; ++e) {
      int r = 32 * w + 16 * e + n;
#pragma unroll
      for (int ks = 0; ks < 2; ++ks)
        Pf[e][ks] = *(const bf16x8*)&sP[r * 64 + (((4 * ks + q) + r) & 7) * 8];
    }
#pragma unroll
    for (int nt = 0; nt < 8; ++nt) {
      int d = 16 * nt + n;
#pragma unroll
      for (int ks = 0; ks < 2; ++ks) {
        bf16x8 vf = *(const bf16x8*)&sVt[d * 64 + (((4 * ks + q) + d) & 7) * 8];
        oacc[0][nt] = MFMA16(Pf[0][ks], vf, oacc[0][nt]);
        oacc[1][nt] = MFMA16(Pf[1][ks], vf, oacc[1][nt]);
      }
    }
    __syncthreads();  // next staging may rewrite sQ; sP/sVt rewritten after A
  }

  // ---- epilogue: O^T bf16 -> sQ (rotated) -> coalesced global partials
#pragma unroll
  for (int e = 0; e < 2; ++e)
#pragma unroll
    for (int nt = 0; nt < 8; ++nt) {
      int d = 16 * nt + n;
      int r0 = 32 * w + 16 * e + 4 * q;
      int G = r0 >> 3, off = 4 * (q & 1);
      uint2 u = {pk2(oacc[e][nt][0], oacc[e][nt][1]),
                 pk2(oacc[e][nt][2], oacc[e][nt][3])};
      *(uint2*)&sQ[d * 128 + ((G + d) & 15) * 8 + off] = u;
    }
  if (q == 0) {
#pragma unroll
    for (int e = 0; e < 2; ++e) {
      int r = 32 * w + 16 * e + n;
      Mpart[(size_t)bid * 128 + r] = m_old[e];
      Lpart[(size_t)bid * 128 + r] = l_old[e];
    }
  }
  __syncthreads();
  for (int i = tid; i < 2048; i += 256) {
    int d = i >> 4, g = i & 15;
    uint4 v = *(const uint4*)&sQ[d * 128 + ((g + d) & 15) * 8];
    *(uint4*)(Opart + (size_t)bid * 16384 + d * 128 + g * 8) = v;
  }
}

// ---------------------------------------------------------------------------
// Combine 32 chunk partials -> A2t bf16 [j=b*16+s][c=h*128+d]
// grid (16 bk, 8 dgrp) x 256
// ---------------------------------------------------------------------------
__global__ __launch_bounds__(256) void combine(const u16* __restrict__ Opart,
                                               const float* __restrict__ Mp,
                                               const float* __restrict__ Lp,
                                               u16* __restrict__ A2t) {
  __shared__ float wgt[32 * 128];  // 16 KB
  const int tid = threadIdx.x;
  const int bk = blockIdx.x, dgrp = blockIdx.y;
  if (tid < 128) {
    int r = tid;
    float mc[32], M = -INFINITY;
#pragma unroll
    for (int c = 0; c < 32; ++c) {
      mc[c] = Mp[(size_t)(bk * 32 + c) * 128 + r];
      M = fmaxf(M, mc[c]);
    }
    float L = 0.f, wv[32];
#pragma unroll
    for (int c = 0; c < 32; ++c) {
      wv[c] = __expf(mc[c] - M);
      L += wv[c] * Lp[(size_t)(bk * 32 + c) * 128 + r];
    }
    float inv = 1.0f / L;
#pragma unroll
    for (int c = 0; c < 32; ++c) wgt[c * 128 + r] = wv[c] * inv;
  }
  __syncthreads();
  int r = tid & 127, dd = tid >> 7;
  int b = bk >> 1, kvh = bk & 1;
  int h = kvh * 8 + (r >> 4), s = r & 15;
  size_t arow = (size_t)(b * 16 + s) * 2048 + h * 128;
  for (int di = 0; di < 8; ++di) {
    int d = dgrp * 16 + dd + 2 * di;
    float o = 0.f;
#pragma unroll
    for (int c = 0; c < 32; ++c)
      o += wgt[c * 128 + r] *
           bf2f(Opart[((size_t)(bk * 32 + c) * 128 + d) * 128 + r]);
    A2t[arow + d] = f2bf(o);
  }
}

// ---------------------------------------------------------------------------
extern "C" void kernel_launch(void* const* d_in, const int* in_sizes, int n_in,
                              void* d_out, int out_size, void* d_ws, size_t ws_size,
                              hipStream_t stream) {
  const float* x    = (const float*)d_in[0];
  const float* cosb = (const float*)d_in[1];
  const float* sinb = (const float*)d_in[2];
  const float* kc   = (const float*)d_in[3];
  const float* vc   = (const float*)d_in[4];
  const int*   posp = (const int*)d_in[5];
  const float* mask = (const float*)d_in[6];
  const float* wq   = (const float*)d_in[7];
  const float* wk   = (const float*)d_in[8];
  const float* wv   = (const float*)d_in[9];
  const float* wo   = (const float*)d_in[10];
  const float* qw   = (const float*)d_in[11];
  const float* kw   = (const float*)d_in[12];

  float* out  = (float*)d_out;
  float* outk = out + 262144;
  float* outv = outk + 16777216;

  float* ws      = (float*)d_ws;
  float* ws_qkv  = ws;                        // 327680 f32 [2560][128]
  float* ws_knew = ws + 327680;               // 32768
  float* ws_vnew = ws + 360448;               // 32768
  u16*   ws_Qa   = (u16*)(ws + 393216);       // 262144 u16
  u16*   ws_Xt   = (u16*)(ws + 524288);       // 262144 u16
  u16*   ws_A2t  = (u16*)(ws + 655360);       // 262144 u16
  float* ws_M    = ws + 786432;               // 65536
  float* ws_L    = ws + 851968;               // 65536
  u16*   ws_O    = (u16*)(ws + 917504);       // 8388608 u16 (bf16 partials)
  // total = 5,111,808 floats = 20.45 MB

  transpose_x<<<256, 256, 0, stream>>>(x, ws_Xt);
  gemm16<0><<<160, 256, 0, stream>>>(wq, wk, wv, ws_Xt, ws_qkv);
  norm_rot<<<640, 256, 0, stream>>>(ws_qkv, cosb, sinb, qw, kw,
                                    ws_Qa, ws_knew, ws_vnew);
  attn<<<512, 256, 0, stream>>>(ws_Qa, kc, vc, ws_knew, ws_vnew, posp, mask,
                                outk, outv, ws_O, ws_M, ws_L);
  combine<<<dim3(16, 8), 256, 0, stream>>>(ws_O, ws_M, ws_L, ws_A2t);
  gemm16<1><<<128, 256, 0, stream>>>(wo, wo, wo, ws_A2t, out);
}